// Round 8
// baseline (23.671 us; speedup 1.0000x reference)
//
#include <hip/hip_runtime.h>
#include <math.h>

#define HEADS 4
#define CDIM 128
#define HDIM 512       // HEADS*CDIM
#define FEAT 128
#define NBS 256        // scan blocks; block NBS is the dedicated target block
#define NT 512
#define REG 8          // per-block slot region (window in-degree ~0.03)
#define TGT_SID (NBS * REG)
#define NMAX 64        // max softmax slots in finalize (incl. self-loop)

// =================== K1: scan my edge window + process my matches ===================
// Block NBS is dedicated to the target node (self-loop): starts its pipeline at t=0,
// overlapping the other blocks' edge scan. No global atomics, no fences — the kernel
// boundary publishes plain stores (rounds 4/6: device-scope fences cost more than a
// launch gap on gfx950).
__global__ __launch_bounds__(NT)
void scan_process_kernel(const float* __restrict__ des, const float* __restrict__ tw,
                         const float* __restrict__ npr, const float* __restrict__ cpr,
                         const float* __restrict__ Wd, const float* __restrict__ bd,
                         const float* __restrict__ Wt, const float* __restrict__ bt,
                         const float* __restrict__ Wn, const float* __restrict__ bn,
                         const float* __restrict__ Wc, const float* __restrict__ bc,
                         const float* __restrict__ Wg, const float* __restrict__ Wo1,
                         const float* __restrict__ att_src, const float* __restrict__ att_dst,
                         const int* __restrict__ ei, int E,
                         const int* __restrict__ tgt_p,
                         int* __restrict__ blockCounts,
                         float* __restrict__ aS, float* __restrict__ aD,
                         float* __restrict__ h_all) {
    __shared__ float sdes[768];
    __shared__ float stw[768];
    __shared__ float snp8[8];
    __shared__ float sfeat[FEAT];
    __shared__ float part[NT];
    __shared__ float pr[2 * HDIM];
    __shared__ int   lmatch[REG];
    __shared__ int   lcount;

    const int tid = threadIdx.x;
    const int b = blockIdx.x;
    const int tgt = *tgt_p;
    const int wv = tid >> 6, lane = tid & 63;

    // ---- one node pipeline: feature -> h -> logits ----
    auto process_node = [&](int node, int sid, bool isTgt) {
        if (tid < 192) {
            ((float4*)sdes)[tid] = ((const float4*)(des + (size_t)node * 768))[tid];
            ((float4*)stw)[tid]  = ((const float4*)(tw  + (size_t)node * 768))[tid];
        } else if (tid < 197) {
            snp8[tid - 192] = npr[node * 5 + (tid - 192)];
        } else if (tid == 197) {
            snp8[5] = cpr[node];
        }
        __syncthreads();

        {   // halves: [0,256) des@Wd, [256,512) tweet@Wt ; 8 chunks x 96, dual-acc
            const int half = tid >> 8;
            const int t2 = tid & 255;
            const int j = t2 & 31, ch = t2 >> 5;
            const float* W = half ? Wt : Wd;
            const float* S = half ? stw : sdes;
            const float* wp = W + (size_t)(ch * 96) * 32 + j;
            const float* sp = S + ch * 96;
            float p0 = 0.f, p1 = 0.f;
            #pragma unroll 24
            for (int k = 0; k < 96; k += 2) {
                p0 = fmaf(sp[k],     wp[(size_t)k * 32],       p0);
                p1 = fmaf(sp[k + 1], wp[(size_t)(k + 1) * 32], p1);
            }
            part[tid] = p0 + p1;
        }
        __syncthreads();
        if (tid < 32) {
            float a = bd[tid];
            #pragma unroll
            for (int c2 = 0; c2 < 8; ++c2) a += part[c2 * 32 + tid];
            sfeat[tid] = a > 0.f ? a : 0.01f * a;
        } else if (tid < 64) {
            const int jj = tid - 32;
            float a = bt[jj];
            #pragma unroll
            for (int c2 = 0; c2 < 8; ++c2) a += part[256 + c2 * 32 + jj];
            sfeat[32 + jj] = a > 0.f ? a : 0.01f * a;
        } else if (tid < 96) {
            const int jj = tid - 64;
            float a = bn[jj];
            #pragma unroll
            for (int k = 0; k < 5; ++k) a = fmaf(snp8[k], Wn[k * 32 + jj], a);
            sfeat[64 + jj] = a > 0.f ? a : 0.01f * a;
        } else if (tid < 128) {
            const int jj = tid - 96;
            float a = fmaf(snp8[5], Wc[jj], bc[jj]);
            sfeat[96 + jj] = a > 0.f ? a : 0.01f * a;
        }
        __syncthreads();

        {   // h = feat @ Wg : one output/thread, coalesced columns, dual-acc
            const float* wg = Wg + tid;
            float h0 = 0.f, h1 = 0.f;
            #pragma unroll 32
            for (int k = 0; k < FEAT; k += 2) {
                h0 = fmaf(sfeat[k],     wg[(size_t)k * HDIM],       h0);
                h1 = fmaf(sfeat[k + 1], wg[(size_t)(k + 1) * HDIM], h1);
            }
            const float hv = h0 + h1;
            h_all[(size_t)sid * HDIM + tid] = hv;
            pr[tid] = hv * att_src[tid];
            if (isTgt) pr[HDIM + tid] = hv * att_dst[tid];
        }
        __syncthreads();

        if (wv < 4) {
            float v = pr[wv * 128 + lane] + pr[wv * 128 + 64 + lane];
            #pragma unroll
            for (int off = 32; off > 0; off >>= 1) v += __shfl_down(v, off);
            if (lane == 0) aS[sid * HEADS + wv] = v;
        } else if (isTgt) {
            const int hd = wv - 4;
            float v = pr[HDIM + hd * 128 + lane] + pr[HDIM + hd * 128 + 64 + lane];
            #pragma unroll
            for (int off = 32; off > 0; off >>= 1) v += __shfl_down(v, off);
            if (lane == 0) aD[hd] = v;
        }
        __syncthreads();
    };

    if (b == NBS) {
        // ---- dedicated target block: pipeline from t=0, overlapping the scan ----
        process_node(tgt, TGT_SID, true);
        return;
    }

    // ---- weight prefetch into L3 (coalesced), consumed after the scan ----
    float keep = 0.f;
    {
        const int g = b * NT + tid;
        if (g < 6144)       { float4 v = ((const float4*)Wd)[g];           keep = v.x + v.y + v.z + v.w; }
        else if (g < 12288) { float4 v = ((const float4*)Wt)[g - 6144];    keep = v.x + v.y + v.z + v.w; }
        else if (g < 28672) { float4 v = ((const float4*)Wg)[g - 12288];   keep = v.x + v.y + v.z + v.w; }
        else if (g < 30848) { float4 v = ((const float4*)Wo1)[g - 28672];  keep = v.x + v.y + v.z + v.w; }
    }

    // ---- scan my contiguous edge window (LDS-local match list) ----
    if (tid == 0) lcount = 0;
    __syncthreads();
    const int nquad = E >> 2;
    const int qb = (nquad + NBS - 1) / NBS;
    const int q0 = b * qb;
    const int qe = (q0 + qb < nquad) ? (q0 + qb) : nquad;
    for (int q = q0 + tid; q < qe; q += NT) {
        const int4 dd = *(const int4*)(ei + (size_t)E + (size_t)q * 4);
        const int base = q * 4;
        if (dd.x == tgt) { int p = atomicAdd(&lcount, 1); if (p < REG) lmatch[p] = ei[base + 0]; }
        if (dd.y == tgt) { int p = atomicAdd(&lcount, 1); if (p < REG) lmatch[p] = ei[base + 1]; }
        if (dd.z == tgt) { int p = atomicAdd(&lcount, 1); if (p < REG) lmatch[p] = ei[base + 2]; }
        if (dd.w == tgt) { int p = atomicAdd(&lcount, 1); if (p < REG) lmatch[p] = ei[base + 3]; }
    }
    if (b == NBS - 1) {
        for (int k = nquad * 4 + tid; k < E; k += NT)
            if (ei[E + k] == tgt) { int p = atomicAdd(&lcount, 1); if (p < REG) lmatch[p] = ei[k]; }
    }
    asm volatile("" :: "v"(keep));   // keep prefetch loads alive
    __syncthreads();

    const int mycount = (lcount < REG) ? lcount : REG;
    if (tid == 0) blockCounts[b] = mycount;   // plain store; kernel boundary publishes

    for (int it = 0; it < mycount; ++it)
        process_node(lmatch[it], b * REG + it, false);
}

// =================== K2: compact slots, softmax-aggregate, MLP ===================
__global__ __launch_bounds__(NT)
void finalize_kernel(const float* __restrict__ x, const float* __restrict__ bgat,
                     const float* __restrict__ Wo1, const float* __restrict__ bo1,
                     const float* __restrict__ Wo2, const float* __restrict__ bo2,
                     const int* __restrict__ blockCounts,
                     const float* __restrict__ aS, const float* __restrict__ aD,
                     const float* __restrict__ h_all,
                     float* __restrict__ out) {
    __shared__ int   sbc[NBS];
    __shared__ int   pf[NBS];
    __shared__ int   wtot[4];        // per-wave totals for scan combine
    __shared__ int   slots[NMAX];
    __shared__ float saS[NMAX * HEADS];
    __shared__ float saD[HEADS];
    __shared__ float pr[HDIM];
    __shared__ float scomb[144];
    __shared__ float shmid[64];
    __shared__ int   sM;

    const int tid = threadIdx.x;
    const int lane = tid & 63;

    // ---- wave-shfl inclusive prefix scan over NBS=256 counts (4 waves of 64) ----
    if (tid < NBS) {
        const int v = blockCounts[tid];
        sbc[tid] = v;
        int s = v;
        #pragma unroll
        for (int off = 1; off < 64; off <<= 1) {
            const int n = __shfl_up(s, off);
            if (lane >= off) s += n;
        }
        pf[tid] = s;
        if (lane == 63) wtot[tid >> 6] = s;
    }
    __syncthreads();
    if (tid < NBS) {
        const int w = tid >> 6;
        int add = 0;
        #pragma unroll
        for (int p = 0; p < 3; ++p) if (w > p) add += wtot[p];
        pf[tid] += add;
    }
    __syncthreads();
    if (tid < NBS) {
        const int excl = pf[tid] - sbc[tid];
        for (int i = 0; i < sbc[tid]; ++i) {
            const int p = excl + i;
            if (p < NMAX - 1) slots[p] = tid * REG + i;
        }
    }
    if (tid == 0) {
        int total = pf[NBS - 1];
        if (total > NMAX - 1) total = NMAX - 1;
        slots[total] = TGT_SID;
        sM = total + 1;
    }
    __syncthreads();
    const int M = sM;

    // stage logits into LDS
    for (int i = tid; i < M * HEADS; i += NT) {
        const int s = i >> 2, hd = i & 3;
        saS[i] = aS[slots[s] * HEADS + hd];
    }
    if (tid < HEADS) saD[tid] = aD[tid];
    __syncthreads();

    // softmax-weighted aggregate: one output channel per thread (512 = HDIM)
    {
        const int o = tid, hd = o >> 7;
        const float adv = saD[hd];
        float m = -INFINITY;
        for (int s = 0; s < M; ++s) {
            float e = saS[s * HEADS + hd] + adv;
            e = e > 0.f ? e : 0.2f * e;     // leaky_relu slope 0.2
            m = fmaxf(m, e);
        }
        float denom = 0.f, acc = 0.f;
        for (int s = 0; s < M; ++s) {
            float e = saS[s * HEADS + hd] + adv;
            e = e > 0.f ? e : 0.2f * e;
            const float ex = expf(e - m);
            denom += ex;
            acc = fmaf(ex, h_all[(size_t)slots[s] * HDIM + o], acc);
        }
        pr[o] = acc / denom;
    }
    __syncthreads();

    if (tid < 128) {
        scomb[tid] = (pr[tid] + pr[128 + tid] + pr[256 + tid] + pr[384 + tid]) * 0.25f
                     + bgat[tid];
    } else if (tid < 136) {
        scomb[tid] = x[tid - 128];
    }
    __syncthreads();

    if (tid < 64) {
        float a = bo1[tid];
        #pragma unroll 8
        for (int k = 0; k < 136; ++k) a = fmaf(scomb[k], Wo1[k * 64 + tid], a);
        shmid[tid] = a > 0.f ? a : 0.f;
    }
    __syncthreads();
    if (tid < 5) {
        float a = bo2[tid];
        #pragma unroll 8
        for (int k = 0; k < 64; ++k) a = fmaf(shmid[k], Wo2[k * 5 + tid], a);
        out[tid] = a;
    }
}

extern "C" void kernel_launch(void* const* d_in, const int* in_sizes, int n_in,
                              void* d_out, int out_size, void* d_ws, size_t ws_size,
                              hipStream_t stream) {
    const float* x    = (const float*)d_in[0];
    const float* des  = (const float*)d_in[1];
    const float* tw   = (const float*)d_in[2];
    const float* npr  = (const float*)d_in[3];
    const float* cpr  = (const float*)d_in[4];
    const int*   ei   = (const int*)d_in[5];     // [2, E] flat
    const int*   tgt  = (const int*)d_in[6];
    const float* Wd   = (const float*)d_in[7];   const float* bd  = (const float*)d_in[8];
    const float* Wt   = (const float*)d_in[9];   const float* bt  = (const float*)d_in[10];
    const float* Wn   = (const float*)d_in[11];  const float* bn  = (const float*)d_in[12];
    const float* Wc   = (const float*)d_in[13];  const float* bc  = (const float*)d_in[14];
    const float* Wg   = (const float*)d_in[15];
    const float* as_  = (const float*)d_in[16];  const float* ad_ = (const float*)d_in[17];
    const float* bg   = (const float*)d_in[18];
    const float* Wo1  = (const float*)d_in[19];  const float* bo1 = (const float*)d_in[20];
    const float* Wo2  = (const float*)d_in[21];  const float* bo2 = (const float*)d_in[22];

    const int E = in_sizes[5] / 2;

    // ws: blockCounts[256] | aS[(TGT_SID+1)*4] | aD[4] | h_all[(TGT_SID+1)*512]
    char* ws = (char*)d_ws;
    int*   blockCounts = (int*)ws;
    float* aS    = (float*)(ws + 2048);
    float* aD    = aS + (size_t)(TGT_SID + 1) * HEADS;
    float* h_all = aD + 16;

    scan_process_kernel<<<NBS + 1, NT, 0, stream>>>(des, tw, npr, cpr,
                                                    Wd, bd, Wt, bt, Wn, bn, Wc, bc,
                                                    Wg, Wo1, as_, ad_,
                                                    ei, E, tgt,
                                                    blockCounts, aS, aD, h_all);

    finalize_kernel<<<1, NT, 0, stream>>>(x, bg, Wo1, bo1, Wo2, bo2,
                                          blockCounts, aS, aD, h_all, (float*)d_out);
}

// Round 9
// 19.453 us; speedup vs baseline: 1.2168x; 1.2168x over previous
//
#include <hip/hip_runtime.h>
#include <math.h>

#define HEADS 4
#define CDIM 128
#define HDIM 512       // HEADS*CDIM
#define FEAT 128
#define NBS 128        // scan blocks; block NBS is the dedicated target block
#define NT 512
#define REG 8          // per-block slot region (window in-degree ~0.06)
#define TGT_SID (NBS * REG)
#define NMAX 64        // max softmax slots in finalize (incl. self-loop)

// =================== K1: scan my edge window + process my matches ===================
// Block NBS is dedicated to the target node (self-loop): starts its pipeline at t=0,
// overlapping the other blocks' edge scan. No global atomics, no fences — the kernel
// boundary publishes plain stores (rounds 4/6: device-scope fences cost more than a
// launch gap on gfx950).
__global__ __launch_bounds__(NT)
void scan_process_kernel(const float* __restrict__ des, const float* __restrict__ tw,
                         const float* __restrict__ npr, const float* __restrict__ cpr,
                         const float* __restrict__ Wd, const float* __restrict__ bd,
                         const float* __restrict__ Wt, const float* __restrict__ bt,
                         const float* __restrict__ Wn, const float* __restrict__ bn,
                         const float* __restrict__ Wc, const float* __restrict__ bc,
                         const float* __restrict__ Wg, const float* __restrict__ Wo1,
                         const float* __restrict__ att_src, const float* __restrict__ att_dst,
                         const int* __restrict__ ei, int E,
                         const int* __restrict__ tgt_p,
                         int* __restrict__ blockCounts,
                         float* __restrict__ aS, float* __restrict__ aD,
                         float* __restrict__ h_all) {
    __shared__ float sdes[768];
    __shared__ float stw[768];
    __shared__ float snp8[8];
    __shared__ float sfeat[FEAT];
    __shared__ float part[NT];
    __shared__ float pr[2 * HDIM];
    __shared__ int   lmatch[REG];
    __shared__ int   lcount;

    const int tid = threadIdx.x;
    const int b = blockIdx.x;
    const int tgt = *tgt_p;
    const int wv = tid >> 6, lane = tid & 63;

    // ---- one node pipeline: feature -> h -> logits ----
    auto process_node = [&](int node, int sid, bool isTgt) {
        if (tid < 192) {
            ((float4*)sdes)[tid] = ((const float4*)(des + (size_t)node * 768))[tid];
            ((float4*)stw)[tid]  = ((const float4*)(tw  + (size_t)node * 768))[tid];
        } else if (tid < 197) {
            snp8[tid - 192] = npr[node * 5 + (tid - 192)];
        } else if (tid == 197) {
            snp8[5] = cpr[node];
        }
        __syncthreads();

        {   // halves: [0,256) des@Wd, [256,512) tweet@Wt ; 8 chunks x 96
            const int half = tid >> 8;
            const int t2 = tid & 255;
            const int j = t2 & 31, ch = t2 >> 5;
            const float* W = half ? Wt : Wd;
            const float* S = half ? stw : sdes;
            const float* wp = W + (size_t)(ch * 96) * 32 + j;
            const float* sp = S + ch * 96;
            float p = 0.f;
            #pragma unroll 16
            for (int k = 0; k < 96; ++k) p = fmaf(sp[k], wp[(size_t)k * 32], p);
            part[tid] = p;
        }
        __syncthreads();
        if (tid < 32) {
            float a = bd[tid];
            #pragma unroll
            for (int c2 = 0; c2 < 8; ++c2) a += part[c2 * 32 + tid];
            sfeat[tid] = a > 0.f ? a : 0.01f * a;
        } else if (tid < 64) {
            const int jj = tid - 32;
            float a = bt[jj];
            #pragma unroll
            for (int c2 = 0; c2 < 8; ++c2) a += part[256 + c2 * 32 + jj];
            sfeat[32 + jj] = a > 0.f ? a : 0.01f * a;
        } else if (tid < 96) {
            const int jj = tid - 64;
            float a = bn[jj];
            #pragma unroll
            for (int k = 0; k < 5; ++k) a = fmaf(snp8[k], Wn[k * 32 + jj], a);
            sfeat[64 + jj] = a > 0.f ? a : 0.01f * a;
        } else if (tid < 128) {
            const int jj = tid - 96;
            float a = fmaf(snp8[5], Wc[jj], bc[jj]);
            sfeat[96 + jj] = a > 0.f ? a : 0.01f * a;
        }
        __syncthreads();

        {   // h = feat @ Wg : one output/thread, coalesced columns
            const float* wg = Wg + tid;
            float hv = 0.f;
            #pragma unroll 16
            for (int k = 0; k < FEAT; ++k) hv = fmaf(sfeat[k], wg[(size_t)k * HDIM], hv);
            h_all[(size_t)sid * HDIM + tid] = hv;
            pr[tid] = hv * att_src[tid];
            if (isTgt) pr[HDIM + tid] = hv * att_dst[tid];
        }
        __syncthreads();

        if (wv < 4) {
            float v = pr[wv * 128 + lane] + pr[wv * 128 + 64 + lane];
            #pragma unroll
            for (int off = 32; off > 0; off >>= 1) v += __shfl_down(v, off);
            if (lane == 0) aS[sid * HEADS + wv] = v;
        } else if (isTgt) {
            const int hd = wv - 4;
            float v = pr[HDIM + hd * 128 + lane] + pr[HDIM + hd * 128 + 64 + lane];
            #pragma unroll
            for (int off = 32; off > 0; off >>= 1) v += __shfl_down(v, off);
            if (lane == 0) aD[hd] = v;
        }
        __syncthreads();
    };

    if (b == NBS) {
        // ---- dedicated target block: pipeline from t=0, overlapping the scan ----
        process_node(tgt, TGT_SID, true);
        return;
    }

    // ---- weight prefetch into L3 (coalesced), consumed after the scan ----
    float keep = 0.f;
    {
        const int g = b * NT + tid;
        if (g < 6144)       { float4 v = ((const float4*)Wd)[g];           keep = v.x + v.y + v.z + v.w; }
        else if (g < 12288) { float4 v = ((const float4*)Wt)[g - 6144];    keep = v.x + v.y + v.z + v.w; }
        else if (g < 28672) { float4 v = ((const float4*)Wg)[g - 12288];   keep = v.x + v.y + v.z + v.w; }
        else if (g < 30848) { float4 v = ((const float4*)Wo1)[g - 28672];  keep = v.x + v.y + v.z + v.w; }
    }

    // ---- scan my contiguous edge window (LDS-local match list) ----
    // On match: the finding thread immediately touch-loads the node's des/tweet rows
    // (one load per 128B line) so they're L2-hot when process_node stages them.
    auto warm_rows = [&](int node) {
        const float4* d4 = (const float4*)(des + (size_t)node * 768);
        const float4* t4 = (const float4*)(tw  + (size_t)node * 768);
        #pragma unroll
        for (int t = 0; t < 192; t += 8) { keep += d4[t].x; keep += t4[t].x; }
    };

    if (tid == 0) lcount = 0;
    __syncthreads();
    const int nquad = E >> 2;
    const int qb = (nquad + NBS - 1) / NBS;
    const int q0 = b * qb;
    const int qe = (q0 + qb < nquad) ? (q0 + qb) : nquad;
    for (int q = q0 + tid; q < qe; q += NT) {
        const int4 dd = *(const int4*)(ei + (size_t)E + (size_t)q * 4);
        const int base = q * 4;
        if (dd.x == tgt) { int p = atomicAdd(&lcount, 1); int n = ei[base + 0]; if (p < REG) lmatch[p] = n; warm_rows(n); }
        if (dd.y == tgt) { int p = atomicAdd(&lcount, 1); int n = ei[base + 1]; if (p < REG) lmatch[p] = n; warm_rows(n); }
        if (dd.z == tgt) { int p = atomicAdd(&lcount, 1); int n = ei[base + 2]; if (p < REG) lmatch[p] = n; warm_rows(n); }
        if (dd.w == tgt) { int p = atomicAdd(&lcount, 1); int n = ei[base + 3]; if (p < REG) lmatch[p] = n; warm_rows(n); }
    }
    if (b == NBS - 1) {
        for (int k = nquad * 4 + tid; k < E; k += NT)
            if (ei[E + k] == tgt) { int p = atomicAdd(&lcount, 1); int n = ei[k]; if (p < REG) lmatch[p] = n; warm_rows(n); }
    }
    asm volatile("" :: "v"(keep));   // keep prefetch/warm loads alive
    __syncthreads();

    const int mycount = (lcount < REG) ? lcount : REG;
    if (tid == 0) blockCounts[b] = mycount;   // plain store; kernel boundary publishes

    for (int it = 0; it < mycount; ++it)
        process_node(lmatch[it], b * REG + it, false);
}

// =================== K2: compact slots, softmax-aggregate, MLP ===================
__global__ __launch_bounds__(NT)
void finalize_kernel(const float* __restrict__ x, const float* __restrict__ bgat,
                     const float* __restrict__ Wo1, const float* __restrict__ bo1,
                     const float* __restrict__ Wo2, const float* __restrict__ bo2,
                     const int* __restrict__ blockCounts,
                     const float* __restrict__ aS, const float* __restrict__ aD,
                     const float* __restrict__ h_all,
                     float* __restrict__ out) {
    __shared__ int   sbc[NBS];
    __shared__ int   pf[NBS];
    __shared__ int   slots[NMAX];
    __shared__ float saS[NMAX * HEADS];
    __shared__ float saD[HEADS];
    __shared__ float pr[HDIM];
    __shared__ float scomb[144];
    __shared__ float shmid[64];
    __shared__ int   sM;

    const int tid = threadIdx.x;

    // ---- single-wave inclusive prefix scan over 128 counts (2 entries/lane) ----
    if (tid < 64) {
        const int v0 = blockCounts[2 * tid];
        const int v1 = blockCounts[2 * tid + 1];
        sbc[2 * tid] = v0;
        sbc[2 * tid + 1] = v1;
        int s = v0 + v1;
        #pragma unroll
        for (int off = 1; off < 64; off <<= 1) {
            const int n = __shfl_up(s, off);
            if (tid >= off) s += n;
        }
        pf[2 * tid]     = s - v1;
        pf[2 * tid + 1] = s;
    }
    if (tid < HEADS) saD[tid] = aD[tid];   // independent early load
    __syncthreads();

    if (tid < NBS) {
        const int excl = pf[tid] - sbc[tid];
        for (int i = 0; i < sbc[tid]; ++i) {
            const int p = excl + i;
            if (p < NMAX - 1) slots[p] = tid * REG + i;
        }
    }
    if (tid == 0) {
        int total = pf[NBS - 1];
        if (total > NMAX - 1) total = NMAX - 1;
        slots[total] = TGT_SID;
        sM = total + 1;
    }
    __syncthreads();
    const int M = sM;

    // stage logits into LDS
    for (int i = tid; i < M * HEADS; i += NT) {
        const int s = i >> 2, hd = i & 3;
        saS[i] = aS[slots[s] * HEADS + hd];
    }
    __syncthreads();

    // softmax-weighted aggregate: one output channel per thread (512 = HDIM)
    {
        const int o = tid, hd = o >> 7;
        const float adv = saD[hd];
        float m = -INFINITY;
        for (int s = 0; s < M; ++s) {
            float e = saS[s * HEADS + hd] + adv;
            e = e > 0.f ? e : 0.2f * e;     // leaky_relu slope 0.2
            m = fmaxf(m, e);
        }
        float denom = 0.f, acc = 0.f;
        for (int s = 0; s < M; ++s) {
            float e = saS[s * HEADS + hd] + adv;
            e = e > 0.f ? e : 0.2f * e;
            const float ex = expf(e - m);
            denom += ex;
            acc = fmaf(ex, h_all[(size_t)slots[s] * HDIM + o], acc);
        }
        pr[o] = acc / denom;
    }
    __syncthreads();

    if (tid < 128) {
        scomb[tid] = (pr[tid] + pr[128 + tid] + pr[256 + tid] + pr[384 + tid]) * 0.25f
                     + bgat[tid];
    } else if (tid < 136) {
        scomb[tid] = x[tid - 128];
    }
    __syncthreads();

    if (tid < 64) {
        float a = bo1[tid];
        #pragma unroll 8
        for (int k = 0; k < 136; ++k) a = fmaf(scomb[k], Wo1[k * 64 + tid], a);
        shmid[tid] = a > 0.f ? a : 0.f;
    }
    __syncthreads();
    if (tid < 5) {
        float a = bo2[tid];
        #pragma unroll 8
        for (int k = 0; k < 64; ++k) a = fmaf(shmid[k], Wo2[k * 5 + tid], a);
        out[tid] = a;
    }
}

extern "C" void kernel_launch(void* const* d_in, const int* in_sizes, int n_in,
                              void* d_out, int out_size, void* d_ws, size_t ws_size,
                              hipStream_t stream) {
    const float* x    = (const float*)d_in[0];
    const float* des  = (const float*)d_in[1];
    const float* tw   = (const float*)d_in[2];
    const float* npr  = (const float*)d_in[3];
    const float* cpr  = (const float*)d_in[4];
    const int*   ei   = (const int*)d_in[5];     // [2, E] flat
    const int*   tgt  = (const int*)d_in[6];
    const float* Wd   = (const float*)d_in[7];   const float* bd  = (const float*)d_in[8];
    const float* Wt   = (const float*)d_in[9];   const float* bt  = (const float*)d_in[10];
    const float* Wn   = (const float*)d_in[11];  const float* bn  = (const float*)d_in[12];
    const float* Wc   = (const float*)d_in[13];  const float* bc  = (const float*)d_in[14];
    const float* Wg   = (const float*)d_in[15];
    const float* as_  = (const float*)d_in[16];  const float* ad_ = (const float*)d_in[17];
    const float* bg   = (const float*)d_in[18];
    const float* Wo1  = (const float*)d_in[19];  const float* bo1 = (const float*)d_in[20];
    const float* Wo2  = (const float*)d_in[21];  const float* bo2 = (const float*)d_in[22];

    const int E = in_sizes[5] / 2;

    // ws: blockCounts[128] | aS[(TGT_SID+1)*4] | aD[4] | h_all[(TGT_SID+1)*512]
    char* ws = (char*)d_ws;
    int*   blockCounts = (int*)ws;
    float* aS    = (float*)(ws + 1024);
    float* aD    = aS + (size_t)(TGT_SID + 1) * HEADS;
    float* h_all = aD + 16;

    scan_process_kernel<<<NBS + 1, NT, 0, stream>>>(des, tw, npr, cpr,
                                                    Wd, bd, Wt, bt, Wn, bn, Wc, bc,
                                                    Wg, Wo1, as_, ad_,
                                                    ei, E, tgt,
                                                    blockCounts, aS, aD, h_all);

    finalize_kernel<<<1, NT, 0, stream>>>(x, bg, Wo1, bo1, Wo2, bo2,
                                          blockCounts, aS, aD, h_all, (float*)d_out);
}

// Round 10
// 18.941 us; speedup vs baseline: 1.2497x; 1.0270x over previous
//
#include <hip/hip_runtime.h>
#include <math.h>

#define HEADS 4
#define CDIM 128
#define HDIM 512       // HEADS*CDIM
#define FEAT 128
#define NBS 128        // scan blocks; block NBS is the dedicated target block
#define NT 512
#define REG 8          // per-block slot region (window in-degree ~0.06)
#define TGT_SID (NBS * REG)
#define NMAX 64        // max softmax slots in finalize (incl. self-loop)

// =================== K1: scan my edge window + process my matches ===================
// Structure identical to round 7/9 (best = 19.1 us). This round: float4 weight loads
// with k-split LDS partials in both GEMVs — 4x fewer VMEM instructions on the
// dominant per-CU weight-read path (450 KB/block), shorter FMA chains.
__global__ __launch_bounds__(NT)
void scan_process_kernel(const float* __restrict__ des, const float* __restrict__ tw,
                         const float* __restrict__ npr, const float* __restrict__ cpr,
                         const float* __restrict__ Wd, const float* __restrict__ bd,
                         const float* __restrict__ Wt, const float* __restrict__ bt,
                         const float* __restrict__ Wn, const float* __restrict__ bn,
                         const float* __restrict__ Wc, const float* __restrict__ bc,
                         const float* __restrict__ Wg, const float* __restrict__ Wo1,
                         const float* __restrict__ att_src, const float* __restrict__ att_dst,
                         const int* __restrict__ ei, int E,
                         const int* __restrict__ tgt_p,
                         int* __restrict__ blockCounts,
                         float* __restrict__ aS, float* __restrict__ aD,
                         float* __restrict__ h_all) {
    __shared__ float sdes[768];
    __shared__ float stw[768];
    __shared__ float snp8[8];
    __shared__ float sfeat[FEAT];
    __shared__ float wpart[2048];    // k-split partials (8 KB), reused by both GEMVs
    __shared__ float pr[2 * HDIM];
    __shared__ int   lmatch[REG];
    __shared__ int   lcount;

    const int tid = threadIdx.x;
    const int b = blockIdx.x;
    const int tgt = *tgt_p;
    const int wv = tid >> 6, lane = tid & 63;

    // ---- one node pipeline: feature -> h -> logits ----
    auto process_node = [&](int node, int sid, bool isTgt) {
        if (tid < 192) {
            ((float4*)sdes)[tid] = ((const float4*)(des + (size_t)node * 768))[tid];
            ((float4*)stw)[tid]  = ((const float4*)(tw  + (size_t)node * 768))[tid];
        } else if (tid < 197) {
            snp8[tid - 192] = npr[node * 5 + (tid - 192)];
        } else if (tid == 197) {
            snp8[5] = cpr[node];
        }
        __syncthreads();

        {   // feature GEMV: halves [0,256)=des@Wd, [256,512)=tweet@Wt.
            // Per half: thread = (kc 0..31, oq 0..7); 24 k's per kc; float4 weight rows.
            const int half = tid >> 8;
            const int t2 = tid & 255;
            const int kc = t2 >> 3, oq = t2 & 7;
            const float4* W4 = (const float4*)(half ? Wt : Wd);   // [768][8 quads]
            const float*  S  = half ? stw : sdes;
            const int k0 = kc * 24;
            float ax = 0.f, ay = 0.f, az = 0.f, aw = 0.f;
            #pragma unroll 8
            for (int k = k0; k < k0 + 24; ++k) {
                const float s = S[k];
                const float4 w = W4[(size_t)k * 8 + oq];
                ax = fmaf(s, w.x, ax);
                ay = fmaf(s, w.y, ay);
                az = fmaf(s, w.z, az);
                aw = fmaf(s, w.w, aw);
            }
            float* p = wpart + half * 1024 + kc * 32 + oq * 4;
            p[0] = ax; p[1] = ay; p[2] = az; p[3] = aw;
        }
        __syncthreads();
        if (tid < 64) {          // reduce 32 kc-partials per output
            const int half = tid >> 5, j = tid & 31;
            const float* p = wpart + half * 1024 + j;
            float a = half ? bt[j] : bd[j];
            #pragma unroll 8
            for (int kc = 0; kc < 32; ++kc) a += p[kc * 32];
            sfeat[half * 32 + j] = a > 0.f ? a : 0.01f * a;
        } else if (tid < 96) {
            const int jj = tid - 64;
            float a = bn[jj];
            #pragma unroll
            for (int k = 0; k < 5; ++k) a = fmaf(snp8[k], Wn[k * 32 + jj], a);
            sfeat[64 + jj] = a > 0.f ? a : 0.01f * a;
        } else if (tid < 128) {
            const int jj = tid - 96;
            float a = fmaf(snp8[5], Wc[jj], bc[jj]);
            sfeat[96 + jj] = a > 0.f ? a : 0.01f * a;
        }
        __syncthreads();

        {   // h GEMV: thread = (kg 0..3, o4 0..127); 32 k's per kg; float4 columns.
            const int kg = tid >> 7, o4 = tid & 127;
            const float4* Wg4 = (const float4*)Wg;   // [128][128 quads]
            const int k0 = kg * 32;
            float ax = 0.f, ay = 0.f, az = 0.f, aw = 0.f;
            #pragma unroll 8
            for (int k = k0; k < k0 + 32; ++k) {
                const float f = sfeat[k];
                const float4 w = Wg4[(size_t)k * 128 + o4];
                ax = fmaf(f, w.x, ax);
                ay = fmaf(f, w.y, ay);
                az = fmaf(f, w.z, az);
                aw = fmaf(f, w.w, aw);
            }
            float* p = wpart + kg * 512 + o4 * 4;
            p[0] = ax; p[1] = ay; p[2] = az; p[3] = aw;
        }
        __syncthreads();
        {   // combine 4 kg-partials; thread tid owns output channel tid
            const float hv = wpart[tid] + wpart[512 + tid] + wpart[1024 + tid] + wpart[1536 + tid];
            h_all[(size_t)sid * HDIM + tid] = hv;
            pr[tid] = hv * att_src[tid];
            if (isTgt) pr[HDIM + tid] = hv * att_dst[tid];
        }
        __syncthreads();

        if (wv < 4) {
            float v = pr[wv * 128 + lane] + pr[wv * 128 + 64 + lane];
            #pragma unroll
            for (int off = 32; off > 0; off >>= 1) v += __shfl_down(v, off);
            if (lane == 0) aS[sid * HEADS + wv] = v;
        } else if (isTgt) {
            const int hd = wv - 4;
            float v = pr[HDIM + hd * 128 + lane] + pr[HDIM + hd * 128 + 64 + lane];
            #pragma unroll
            for (int off = 32; off > 0; off >>= 1) v += __shfl_down(v, off);
            if (lane == 0) aD[hd] = v;
        }
        __syncthreads();   // protect LDS before next slot
    };

    if (b == NBS) {
        // ---- dedicated target block: pipeline from t=0, overlapping the scan ----
        process_node(tgt, TGT_SID, true);
        return;
    }

    // ---- weight prefetch into L3 (coalesced), consumed after the scan ----
    float keep = 0.f;
    {
        const int g = b * NT + tid;
        if (g < 6144)       { float4 v = ((const float4*)Wd)[g];           keep = v.x + v.y + v.z + v.w; }
        else if (g < 12288) { float4 v = ((const float4*)Wt)[g - 6144];    keep = v.x + v.y + v.z + v.w; }
        else if (g < 28672) { float4 v = ((const float4*)Wg)[g - 12288];   keep = v.x + v.y + v.z + v.w; }
        else if (g < 30848) { float4 v = ((const float4*)Wo1)[g - 28672];  keep = v.x + v.y + v.z + v.w; }
    }

    // ---- scan my contiguous edge window (LDS-local match list) ----
    // On match: touch-load the node's des/tweet rows so they're L2-hot at staging.
    auto warm_rows = [&](int node) {
        const float4* d4 = (const float4*)(des + (size_t)node * 768);
        const float4* t4 = (const float4*)(tw  + (size_t)node * 768);
        #pragma unroll
        for (int t = 0; t < 192; t += 8) { keep += d4[t].x; keep += t4[t].x; }
    };

    if (tid == 0) lcount = 0;
    __syncthreads();
    const int nquad = E >> 2;
    const int qb = (nquad + NBS - 1) / NBS;
    const int q0 = b * qb;
    const int qe = (q0 + qb < nquad) ? (q0 + qb) : nquad;
    for (int q = q0 + tid; q < qe; q += NT) {
        const int4 dd = *(const int4*)(ei + (size_t)E + (size_t)q * 4);
        const int base = q * 4;
        if (dd.x == tgt) { int p = atomicAdd(&lcount, 1); int n = ei[base + 0]; if (p < REG) lmatch[p] = n; warm_rows(n); }
        if (dd.y == tgt) { int p = atomicAdd(&lcount, 1); int n = ei[base + 1]; if (p < REG) lmatch[p] = n; warm_rows(n); }
        if (dd.z == tgt) { int p = atomicAdd(&lcount, 1); int n = ei[base + 2]; if (p < REG) lmatch[p] = n; warm_rows(n); }
        if (dd.w == tgt) { int p = atomicAdd(&lcount, 1); int n = ei[base + 3]; if (p < REG) lmatch[p] = n; warm_rows(n); }
    }
    if (b == NBS - 1) {
        for (int k = nquad * 4 + tid; k < E; k += NT)
            if (ei[E + k] == tgt) { int p = atomicAdd(&lcount, 1); int n = ei[k]; if (p < REG) lmatch[p] = n; warm_rows(n); }
    }
    asm volatile("" :: "v"(keep));   // keep prefetch/warm loads alive
    __syncthreads();

    const int mycount = (lcount < REG) ? lcount : REG;
    if (tid == 0) blockCounts[b] = mycount;   // plain store; kernel boundary publishes

    for (int it = 0; it < mycount; ++it)
        process_node(lmatch[it], b * REG + it, false);
}

// =================== K2: compact slots, softmax-aggregate, MLP ===================
__global__ __launch_bounds__(NT)
void finalize_kernel(const float* __restrict__ x, const float* __restrict__ bgat,
                     const float* __restrict__ Wo1, const float* __restrict__ bo1,
                     const float* __restrict__ Wo2, const float* __restrict__ bo2,
                     const int* __restrict__ blockCounts,
                     const float* __restrict__ aS, const float* __restrict__ aD,
                     const float* __restrict__ h_all,
                     float* __restrict__ out) {
    __shared__ int   sbc[NBS];
    __shared__ int   pf[NBS];
    __shared__ int   slots[NMAX];
    __shared__ float saS[NMAX * HEADS];
    __shared__ float saD[HEADS];
    __shared__ float pr[HDIM];
    __shared__ float scomb[144];
    __shared__ float shmid[64];
    __shared__ int   sM;

    const int tid = threadIdx.x;

    // ---- single-wave inclusive prefix scan over 128 counts (2 entries/lane) ----
    if (tid < 64) {
        const int v0 = blockCounts[2 * tid];
        const int v1 = blockCounts[2 * tid + 1];
        sbc[2 * tid] = v0;
        sbc[2 * tid + 1] = v1;
        int s = v0 + v1;
        #pragma unroll
        for (int off = 1; off < 64; off <<= 1) {
            const int n = __shfl_up(s, off);
            if (tid >= off) s += n;
        }
        pf[2 * tid]     = s - v1;
        pf[2 * tid + 1] = s;
    }
    if (tid < HEADS) saD[tid] = aD[tid];   // independent early load
    __syncthreads();

    if (tid < NBS) {
        const int excl = pf[tid] - sbc[tid];
        for (int i = 0; i < sbc[tid]; ++i) {
            const int p = excl + i;
            if (p < NMAX - 1) slots[p] = tid * REG + i;
        }
    }
    if (tid == 0) {
        int total = pf[NBS - 1];
        if (total > NMAX - 1) total = NMAX - 1;
        slots[total] = TGT_SID;
        sM = total + 1;
    }
    __syncthreads();
    const int M = sM;

    // stage logits into LDS
    for (int i = tid; i < M * HEADS; i += NT) {
        const int s = i >> 2, hd = i & 3;
        saS[i] = aS[slots[s] * HEADS + hd];
    }
    __syncthreads();

    // softmax-weighted aggregate: one output channel per thread (512 = HDIM)
    {
        const int o = tid, hd = o >> 7;
        const float adv = saD[hd];
        float m = -INFINITY;
        for (int s = 0; s < M; ++s) {
            float e = saS[s * HEADS + hd] + adv;
            e = e > 0.f ? e : 0.2f * e;     // leaky_relu slope 0.2
            m = fmaxf(m, e);
        }
        float denom = 0.f, acc = 0.f;
        for (int s = 0; s < M; ++s) {
            float e = saS[s * HEADS + hd] + adv;
            e = e > 0.f ? e : 0.2f * e;
            const float ex = expf(e - m);
            denom += ex;
            acc = fmaf(ex, h_all[(size_t)slots[s] * HDIM + o], acc);
        }
        pr[o] = acc / denom;
    }
    __syncthreads();

    if (tid < 128) {
        scomb[tid] = (pr[tid] + pr[128 + tid] + pr[256 + tid] + pr[384 + tid]) * 0.25f
                     + bgat[tid];
    } else if (tid < 136) {
        scomb[tid] = x[tid - 128];
    }
    __syncthreads();

    if (tid < 64) {
        float a = bo1[tid];
        #pragma unroll 8
        for (int k = 0; k < 136; ++k) a = fmaf(scomb[k], Wo1[k * 64 + tid], a);
        shmid[tid] = a > 0.f ? a : 0.f;
    }
    __syncthreads();
    if (tid < 5) {
        float a = bo2[tid];
        #pragma unroll 8
        for (int k = 0; k < 64; ++k) a = fmaf(shmid[k], Wo2[k * 5 + tid], a);
        out[tid] = a;
    }
}

extern "C" void kernel_launch(void* const* d_in, const int* in_sizes, int n_in,
                              void* d_out, int out_size, void* d_ws, size_t ws_size,
                              hipStream_t stream) {
    const float* x    = (const float*)d_in[0];
    const float* des  = (const float*)d_in[1];
    const float* tw   = (const float*)d_in[2];
    const float* npr  = (const float*)d_in[3];
    const float* cpr  = (const float*)d_in[4];
    const int*   ei   = (const int*)d_in[5];     // [2, E] flat
    const int*   tgt  = (const int*)d_in[6];
    const float* Wd   = (const float*)d_in[7];   const float* bd  = (const float*)d_in[8];
    const float* Wt   = (const float*)d_in[9];   const float* bt  = (const float*)d_in[10];
    const float* Wn   = (const float*)d_in[11];  const float* bn  = (const float*)d_in[12];
    const float* Wc   = (const float*)d_in[13];  const float* bc  = (const float*)d_in[14];
    const float* Wg   = (const float*)d_in[15];
    const float* as_  = (const float*)d_in[16];  const float* ad_ = (const float*)d_in[17];
    const float* bg   = (const float*)d_in[18];
    const float* Wo1  = (const float*)d_in[19];  const float* bo1 = (const float*)d_in[20];
    const float* Wo2  = (const float*)d_in[21];  const float* bo2 = (const float*)d_in[22];

    const int E = in_sizes[5] / 2;

    // ws: blockCounts[128] | aS[(TGT_SID+1)*4] | aD[4] | h_all[(TGT_SID+1)*512]
    char* ws = (char*)d_ws;
    int*   blockCounts = (int*)ws;
    float* aS    = (float*)(ws + 1024);
    float* aD    = aS + (size_t)(TGT_SID + 1) * HEADS;
    float* h_all = aD + 16;

    scan_process_kernel<<<NBS + 1, NT, 0, stream>>>(des, tw, npr, cpr,
                                                    Wd, bd, Wt, bt, Wn, bn, Wc, bc,
                                                    Wg, Wo1, as_, ad_,
                                                    ei, E, tgt,
                                                    blockCounts, aS, aD, h_all);

    finalize_kernel<<<1, NT, 0, stream>>>(x, bg, Wo1, bo1, Wo2, bo2,
                                          blockCounts, aS, aD, h_all, (float*)d_out);
}